// Round 1
// 1395.708 us; speedup vs baseline: 1.7817x; 1.7817x over previous
//
#include <hip/hip_runtime.h>
#include <stdint.h>

#define TSTR 8192
#define CRES 64
#define CSKIP 128
#define SKIPN 4096
#define NB 8
#define NT 64
#define N_LAYERS 40

// repacked weight sizes (elements, per layer, hi+lo interleaved as p-dim)
#define WCAT_L 16384   // [k4][m4][p2][512]
#define WRES_L 8192    // [k2][m4][p2][512]
#define WSKIP_L 16384  // [k2][m8][p2][512]

typedef __attribute__((ext_vector_type(8))) short short8;
typedef __attribute__((ext_vector_type(4))) float f32x4;

#define MFMA16(a, b, c) __builtin_amdgcn_mfma_f32_16x16x32_bf16((a), (b), (c), 0, 0, 0)

__device__ __forceinline__ unsigned short f2bf(float x) {
    unsigned u = __float_as_uint(x);
    unsigned r = (u + 0x7fffu + ((u >> 16) & 1u)) >> 16;   // RNE
    return (unsigned short)r;
}
__device__ __forceinline__ float bf2f(unsigned h) {
    return __uint_as_float((h & 0xffffu) << 16);
}

__device__ __forceinline__ void load_lds16(const unsigned short* g, unsigned short* l) {
    // dest = (wave-uniform LDS base) + lane*16 ; src is per-lane
    __builtin_amdgcn_global_load_lds(
        (const __attribute__((address_space(1))) unsigned int*)g,
        (__attribute__((address_space(3))) unsigned int*)l, 16, 0, 0);
}

// ---------------------------------------------------------------------------
// Repack weights into MFMA A-fragment order, bf16 hi/lo split.
// A-frag (16x16x32): lane l holds A[m = mt*16 + (l&15)][k = ks*32 + (l>>4)*8 + j]
// ---------------------------------------------------------------------------
__global__ void repack_mfma(const float* __restrict__ wdil,
                            const float* __restrict__ wres,
                            const float* __restrict__ wskip,
                            unsigned short* __restrict__ wcatP,
                            unsigned short* __restrict__ wresP,
                            unsigned short* __restrict__ wskipP) {
    const int idx = blockIdx.x * 256 + threadIdx.x;
    const int NC = N_LAYERS * WCAT_L;
    const int NR = N_LAYERS * WRES_L;
    const int NS = N_LAYERS * WSKIP_L;
    if (idx < NC) {
        int l = idx / WCAT_L, e = idx % WCAT_L;
        int q = e & 511, p = (e >> 9) & 1, m = (e >> 10) & 3, ks = e >> 12;
        int lane = q >> 3, j = q & 7;
        int mc = m * 16 + (lane & 15);
        int k = ks * 32 + (lane >> 4) * 8 + j;
        float v = (k < 64) ? wdil[((l * 64 + mc) * 64 + k) * 2]
                           : wdil[((l * 64 + mc) * 64 + (k - 64)) * 2 + 1];
        unsigned short h = f2bf(v);
        wcatP[idx] = p ? f2bf(v - bf2f(h)) : h;
    } else if (idx < NC + NR) {
        int jdx = idx - NC;
        int l = jdx / WRES_L, e = jdx % WRES_L;
        int q = e & 511, p = (e >> 9) & 1, m = (e >> 10) & 3, ks = e >> 12;
        int lane = q >> 3, j = q & 7;
        int mc = m * 16 + (lane & 15);
        int k = ks * 32 + (lane >> 4) * 8 + j;
        float v = wres[(l * 64 + mc) * 64 + k];
        unsigned short h = f2bf(v);
        wresP[jdx] = p ? f2bf(v - bf2f(h)) : h;
    } else if (idx < NC + NR + NS) {
        int jdx = idx - NC - NR;
        int l = jdx / WSKIP_L, e = jdx % WSKIP_L;
        int q = e & 511, p = (e >> 9) & 1, m = (e >> 10) & 7, ks = e >> 13;
        int lane = q >> 3, j = q & 7;
        int mc = m * 16 + (lane & 15);
        int k = ks * 32 + (lane >> 4) * 8 + j;
        float v = wskip[(l * 128 + mc) * 64 + k];
        unsigned short h = f2bf(v);
        wskipP[jdx] = p ? f2bf(v - bf2f(h)) : h;
    }
}

// ---------------------------------------------------------------------------
// One-time: x [b][c][t] fp32  ->  stream hi/lo bf16 in [b][t][c] layout.
// ---------------------------------------------------------------------------
__global__ __launch_bounds__(256)
void transpose_split(const float* __restrict__ x,
                     unsigned short* __restrict__ shi,
                     unsigned short* __restrict__ slo) {
    __shared__ float Xt[64][65];
    const int tid = threadIdx.x;
    const int lane = tid & 63;
    const int w = tid >> 6;
    const int b = blockIdx.y;
    const int t0 = blockIdx.x * 64;
    const float* xb = x + (size_t)b * CRES * TSTR;
    #pragma unroll
    for (int i = 0; i < 16; i++) {
        const int c = w * 16 + i;
        Xt[c][lane] = xb[(size_t)c * TSTR + t0 + lane];
    }
    __syncthreads();
    const int t = tid >> 2;
    const int cq = (tid & 3) * 16;
    unsigned hw[8], lw[8];
    #pragma unroll
    for (int i = 0; i < 16; i += 2) {
        float v0 = Xt[cq + i][t];
        float v1 = Xt[cq + i + 1][t];
        unsigned short h0 = f2bf(v0), h1 = f2bf(v1);
        unsigned short l0 = f2bf(v0 - bf2f(h0)), l1 = f2bf(v1 - bf2f(h1));
        hw[i >> 1] = (unsigned)h0 | ((unsigned)h1 << 16);
        lw[i >> 1] = (unsigned)l0 | ((unsigned)l1 << 16);
    }
    size_t ob = (((size_t)b * TSTR) + t0 + t) * 64 + cq;
    *(uint4*)(shi + ob)     = make_uint4(hw[0], hw[1], hw[2], hw[3]);
    *(uint4*)(shi + ob + 8) = make_uint4(hw[4], hw[5], hw[6], hw[7]);
    *(uint4*)(slo + ob)     = make_uint4(lw[0], lw[1], lw[2], lw[3]);
    *(uint4*)(slo + ob + 8) = make_uint4(lw[4], lw[5], lw[6], lw[7]);
}

// ---------------------------------------------------------------------------
// Fused layer, MFMA version. Block = 256 threads (4 waves), NT=64 timesteps.
// Wave w owns conv/res out-channel tile [16w,16w+16) and skip tiles w, w+4.
// LDS X layout per (tap,prec): [chunk(8)][t(64)][8ch] -> B-frag reads are
// contiguous 16B per lane (conflict-free). Gated acts G stored same way.
// 3-product bf16 hi/lo split per GEMM (fp32-equivalent precision).
// ---------------------------------------------------------------------------
__global__ __launch_bounds__(256, 3)
void layer_mfma(const unsigned short* __restrict__ in_hi,
                const unsigned short* __restrict__ in_lo,
                unsigned short* __restrict__ out_hi,
                unsigned short* __restrict__ out_lo,
                const unsigned short* __restrict__ wcat,
                const unsigned short* __restrict__ wres,
                const unsigned short* __restrict__ wskip,
                const float* __restrict__ bres,
                const float* __restrict__ bskip,
                float* __restrict__ skipout,
                int d, int Lp, int skip_start, int ntiles) {
    __shared__ __align__(16) unsigned short Xs[2][2][8][NT][8];  // 32 KB
    __shared__ __align__(16) unsigned short Gs[2][8][NT][8];     // 16 KB

    const int tid = threadIdx.x;
    const int lane = tid & 63;
    const int w = tid >> 6;
    const int b = blockIdx.y;

    // bijective XCD-aware tile swizzle (contiguous t-chunks per XCD)
    const int orig = blockIdx.x;
    const int qq = ntiles >> 3, r8 = ntiles & 7;
    const int xcd = orig & 7, sidx = orig >> 3;
    const int tile = (xcd < r8) ? (xcd * (qq + 1) + sidx)
                                : (r8 * (qq + 1) + (xcd - r8) * qq + sidx);
    const int t0 = tile * NT;

    // ---- stage both taps (hi,lo) into LDS; wave w stages segment w ----
    {
        const int tap = w >> 1, prec = w & 1;
        const unsigned short* src = prec ? in_lo : in_hi;
        const int row = min(t0 + lane, Lp - 1) + (tap ? d : 0);
        const unsigned short* gp = src + (((size_t)b * TSTR + row) << 6);
        unsigned short* lp = &Xs[tap][prec][0][0][0];
        #pragma unroll
        for (int c8 = 0; c8 < 8; c8++)
            load_lds16(gp + c8 * 8, lp + c8 * (NT * 8));  // chunk c8, t=lane
    }
    asm volatile("s_waitcnt vmcnt(0)" ::: "memory");
    __syncthreads();

    const int cg = lane >> 4;   // k-chunk group of this lane
    const int lt = lane & 15;   // column (t) within n-tile

    // ---- conv A-frags (held in regs across all n-tiles) ----
    short8 cAh[4], cAl[4];
    #pragma unroll
    for (int ks = 0; ks < 4; ks++) {
        const unsigned short* base = wcat + ((ks * 4 + w) * 2) * 512 + lane * 8;
        cAh[ks] = *(const short8*)base;
        cAl[ks] = *(const short8*)(base + 512);
    }

    // ---- conv + gate + write G ----
    #pragma unroll
    for (int nt = 0; nt < 4; nt++) {
        const int tl = nt * 16 + lt;
        f32x4 acc = {0.f, 0.f, 0.f, 0.f};
        #pragma unroll
        for (int ks = 0; ks < 4; ks++) {
            const int tap = ks >> 1;
            const int ch = (ks & 1) * 4 + cg;
            short8 bh = *(const short8*)&Xs[tap][0][ch][tl][0];
            short8 bl = *(const short8*)&Xs[tap][1][ch][tl][0];
            acc = MFMA16(cAh[ks], bh, acc);
            acc = MFMA16(cAh[ks], bl, acc);
            acc = MFMA16(cAl[ks], bh, acc);
        }
        unsigned short gh[4], gl[4];
        #pragma unroll
        for (int rr = 0; rr < 4; rr++) {
            float y = acc[rr];
            float e = __expf(-y);
            float g = (1.f - e) / fmaf(e, e, 1.f);   // tanh(y)*sigmoid(y)
            gh[rr] = f2bf(g);
            gl[rr] = f2bf(g - bf2f(gh[rr]));
        }
        const int crow = w * 16 + cg * 4;
        const int gch = crow >> 3, gcb = crow & 7;
        *(unsigned*)&Gs[0][gch][tl][gcb]     = (unsigned)gh[0] | ((unsigned)gh[1] << 16);
        *(unsigned*)&Gs[0][gch][tl][gcb + 2] = (unsigned)gh[2] | ((unsigned)gh[3] << 16);
        *(unsigned*)&Gs[1][gch][tl][gcb]     = (unsigned)gl[0] | ((unsigned)gl[1] << 16);
        *(unsigned*)&Gs[1][gch][tl][gcb + 2] = (unsigned)gl[2] | ((unsigned)gl[3] << 16);
    }
    __syncthreads();

    // ---- res + skip GEMMs over G ----
    const bool doSkip = (t0 + NT > skip_start);
    short8 rAh[2], rAl[2];
    #pragma unroll
    for (int ks = 0; ks < 2; ks++) {
        const unsigned short* base = wres + ((ks * 4 + w) * 2) * 512 + lane * 8;
        rAh[ks] = *(const short8*)base;
        rAl[ks] = *(const short8*)(base + 512);
    }
    const int c0 = w * 16 + cg * 4;
    const f32x4 brv = *(const f32x4*)(bres + c0);

    short8 sAh[2][2], sAl[2][2];
    f32x4 bsv[2];
    if (doSkip) {
        #pragma unroll
        for (int sm = 0; sm < 2; sm++) {
            const int m = w + sm * 4;
            #pragma unroll
            for (int ks = 0; ks < 2; ks++) {
                const unsigned short* base = wskip + ((ks * 8 + m) * 2) * 512 + lane * 8;
                sAh[sm][ks] = *(const short8*)base;
                sAl[sm][ks] = *(const short8*)(base + 512);
            }
            bsv[sm] = *(const f32x4*)(bskip + m * 16 + cg * 4);
        }
    }

    float* skb = skipout + (size_t)b * CSKIP * SKIPN;
    unsigned short* ohb = out_hi + (((size_t)b * TSTR) << 6);
    unsigned short* olb = out_lo + (((size_t)b * TSTR) << 6);

    #pragma unroll
    for (int nt = 0; nt < 4; nt++) {
        const int tl = nt * 16 + lt;
        short8 gbh[2], gbl[2];
        #pragma unroll
        for (int ks = 0; ks < 2; ks++) {
            const int ch = ks * 4 + cg;
            gbh[ks] = *(const short8*)&Gs[0][ch][tl][0];
            gbl[ks] = *(const short8*)&Gs[1][ch][tl][0];
        }
        f32x4 racc = {0.f, 0.f, 0.f, 0.f};
        #pragma unroll
        for (int ks = 0; ks < 2; ks++) {
            racc = MFMA16(rAh[ks], gbh[ks], racc);
            racc = MFMA16(rAh[ks], gbl[ks], racc);
            racc = MFMA16(rAl[ks], gbh[ks], racc);
        }
        const int tp = t0 + tl;
        if (tp < Lp) {
            // residual from tap1 (hi+lo reconstruct) + bias, then re-split
            const int xch = c0 >> 3, xcb = c0 & 7;
            unsigned xh01 = *(const unsigned*)&Xs[1][0][xch][tl][xcb];
            unsigned xh23 = *(const unsigned*)&Xs[1][0][xch][tl][xcb + 2];
            unsigned xl01 = *(const unsigned*)&Xs[1][1][xch][tl][xcb];
            unsigned xl23 = *(const unsigned*)&Xs[1][1][xch][tl][xcb + 2];
            float v0 = racc[0] + brv[0] + bf2f(xh01) + bf2f(xl01);
            float v1 = racc[1] + brv[1] + bf2f(xh01 >> 16) + bf2f(xl01 >> 16);
            float v2 = racc[2] + brv[2] + bf2f(xh23) + bf2f(xl23);
            float v3 = racc[3] + brv[3] + bf2f(xh23 >> 16) + bf2f(xl23 >> 16);
            unsigned short oh0 = f2bf(v0), oh1 = f2bf(v1), oh2 = f2bf(v2), oh3 = f2bf(v3);
            uint2 hv, lv;
            hv.x = (unsigned)oh0 | ((unsigned)oh1 << 16);
            hv.y = (unsigned)oh2 | ((unsigned)oh3 << 16);
            lv.x = (unsigned)f2bf(v0 - bf2f(oh0)) | ((unsigned)f2bf(v1 - bf2f(oh1)) << 16);
            lv.y = (unsigned)f2bf(v2 - bf2f(oh2)) | ((unsigned)f2bf(v3 - bf2f(oh3)) << 16);
            const size_t ob = ((size_t)tp << 6) + c0;
            *(uint2*)(ohb + ob) = hv;
            *(uint2*)(olb + ob) = lv;
        }
        if (doSkip) {   // block-uniform: MFMA runs with full exec mask
            #pragma unroll
            for (int sm = 0; sm < 2; sm++) {
                f32x4 sacc = {0.f, 0.f, 0.f, 0.f};
                #pragma unroll
                for (int ks = 0; ks < 2; ks++) {
                    sacc = MFMA16(sAh[sm][ks], gbh[ks], sacc);
                    sacc = MFMA16(sAh[sm][ks], gbl[ks], sacc);
                    sacc = MFMA16(sAl[sm][ks], gbh[ks], sacc);
                }
                if (tp >= skip_start && tp < Lp) {
                    const int c2 = (w + sm * 4) * 16 + cg * 4;
                    float* sp = skb + (size_t)c2 * SKIPN + (tp - skip_start);
                    sp[0]         = sacc[0] + bsv[sm][0];
                    sp[SKIPN]     = sacc[1] + bsv[sm][1];
                    sp[2 * SKIPN] = sacc[2] + bsv[sm][2];
                    sp[3 * SKIPN] = sacc[3] + bsv[sm][3];
                }
            }
        }
    }
}

// ---------------------------------------------------------------------------
// Host: repack + transpose once, then 40 stream-ordered layer launches.
// ws: s0h|s0l|s1h|s1l (4 x 8 MiB) | wcatP | wresP | wskipP  (~35.3 MB)
// ---------------------------------------------------------------------------
extern "C" void kernel_launch(void* const* d_in, const int* in_sizes, int n_in,
                              void* d_out, int out_size, void* d_ws, size_t ws_size,
                              hipStream_t stream) {
    const float* x = (const float*)d_in[0];
    const float* wdil = (const float*)d_in[1];
    const float* wres = (const float*)d_in[2];
    const float* bres = (const float*)d_in[3];
    const float* wskip = (const float*)d_in[4];
    const float* bskip = (const float*)d_in[5];
    float* out = (float*)d_out;

    const size_t SELEMS = (size_t)NB * TSTR * 64;
    unsigned short* s0h = (unsigned short*)d_ws;
    unsigned short* s0l = s0h + SELEMS;
    unsigned short* s1h = s0l + SELEMS;
    unsigned short* s1l = s1h + SELEMS;
    unsigned short* wcatP = s1l + SELEMS;
    unsigned short* wresP = wcatP + (size_t)N_LAYERS * WCAT_L;
    unsigned short* wskipP = wresP + (size_t)N_LAYERS * WRES_L;

    {
        const int total = N_LAYERS * (WCAT_L + WRES_L + WSKIP_L);
        repack_mfma<<<(total + 255) / 256, 256, 0, stream>>>(
            wdil, wres, wskip, wcatP, wresP, wskipP);
    }
    transpose_split<<<dim3(TSTR / 64, NB), 256, 0, stream>>>(x, s0h, s0l);

    int L = TSTR;
    unsigned short *cih = s0h, *cil = s0l, *coh = s1h, *col = s1l;
    for (int i = 0; i < N_LAYERS; i++) {
        const int d = 1 << (i % 10);
        const int Lp = L - d;
        const int ntiles = (Lp + NT - 1) / NT;
        layer_mfma<<<dim3(ntiles, NB), 256, 0, stream>>>(
            cih, cil, coh, col,
            wcatP + (size_t)i * WCAT_L,
            wresP + (size_t)i * WRES_L,
            wskipP + (size_t)i * WSKIP_L,
            bres + (size_t)i * CRES,
            bskip + (size_t)i * CSKIP,
            out + (size_t)i * NB * CSKIP * SKIPN,
            d, Lp, Lp - SKIPN, ntiles);
        unsigned short* th = cih; cih = coh; coh = th;
        unsigned short* tl2 = cil; cil = col; col = tl2;
        L = Lp;
    }
}

// Round 2
// 1249.845 us; speedup vs baseline: 1.9897x; 1.1167x over previous
//
#include <hip/hip_runtime.h>
#include <stdint.h>

#define TSTR 8192
#define CRES 64
#define CSKIP 128
#define SKIPN 4096
#define NB 8
#define NT 64
#define N_LAYERS 40

// repacked weight sizes (elements, per layer, hi+lo interleaved as p-dim)
#define WCAT_L 16384   // [k4][m4][p2][512]
#define WRES_L 8192    // [k2][m4][p2][512]
#define WSKIP_L 16384  // [k2][m8][p2][512]

typedef __attribute__((ext_vector_type(8))) short short8;
typedef __attribute__((ext_vector_type(4))) float f32x4;

#define MFMA16(a, b, c) __builtin_amdgcn_mfma_f32_16x16x32_bf16((a), (b), (c), 0, 0, 0)

__device__ __forceinline__ unsigned short f2bf(float x) {
    unsigned u = __float_as_uint(x);
    unsigned r = (u + 0x7fffu + ((u >> 16) & 1u)) >> 16;   // RNE
    return (unsigned short)r;
}
__device__ __forceinline__ float bf2f(unsigned h) {
    return __uint_as_float((h & 0xffffu) << 16);
}

__device__ __forceinline__ void load_lds16(const unsigned short* g, unsigned short* l) {
    // dest = (wave-uniform LDS base) + lane*16 ; src is per-lane
    __builtin_amdgcn_global_load_lds(
        (const __attribute__((address_space(1))) unsigned int*)g,
        (__attribute__((address_space(3))) unsigned int*)l, 16, 0, 0);
}

// ---------------------------------------------------------------------------
// Repack weights into MFMA A-fragment order, bf16 hi/lo split.
// A-frag (16x16x32): lane l holds A[m = mt*16 + (l&15)][k = ks*32 + (l>>4)*8 + j]
// ---------------------------------------------------------------------------
__global__ void repack_mfma(const float* __restrict__ wdil,
                            const float* __restrict__ wres,
                            const float* __restrict__ wskip,
                            unsigned short* __restrict__ wcatP,
                            unsigned short* __restrict__ wresP,
                            unsigned short* __restrict__ wskipP) {
    const int idx = blockIdx.x * 256 + threadIdx.x;
    const int NC = N_LAYERS * WCAT_L;
    const int NR = N_LAYERS * WRES_L;
    const int NS = N_LAYERS * WSKIP_L;
    if (idx < NC) {
        int l = idx / WCAT_L, e = idx % WCAT_L;
        int q = e & 511, p = (e >> 9) & 1, m = (e >> 10) & 3, ks = e >> 12;
        int lane = q >> 3, j = q & 7;
        int mc = m * 16 + (lane & 15);
        int k = ks * 32 + (lane >> 4) * 8 + j;
        float v = (k < 64) ? wdil[((l * 64 + mc) * 64 + k) * 2]
                           : wdil[((l * 64 + mc) * 64 + (k - 64)) * 2 + 1];
        unsigned short h = f2bf(v);
        wcatP[idx] = p ? f2bf(v - bf2f(h)) : h;
    } else if (idx < NC + NR) {
        int jdx = idx - NC;
        int l = jdx / WRES_L, e = jdx % WRES_L;
        int q = e & 511, p = (e >> 9) & 1, m = (e >> 10) & 3, ks = e >> 12;
        int lane = q >> 3, j = q & 7;
        int mc = m * 16 + (lane & 15);
        int k = ks * 32 + (lane >> 4) * 8 + j;
        float v = wres[(l * 64 + mc) * 64 + k];
        unsigned short h = f2bf(v);
        wresP[jdx] = p ? f2bf(v - bf2f(h)) : h;
    } else if (idx < NC + NR + NS) {
        int jdx = idx - NC - NR;
        int l = jdx / WSKIP_L, e = jdx % WSKIP_L;
        int q = e & 511, p = (e >> 9) & 1, m = (e >> 10) & 7, ks = e >> 13;
        int lane = q >> 3, j = q & 7;
        int mc = m * 16 + (lane & 15);
        int k = ks * 32 + (lane >> 4) * 8 + j;
        float v = wskip[(l * 128 + mc) * 64 + k];
        unsigned short h = f2bf(v);
        wskipP[jdx] = p ? f2bf(v - bf2f(h)) : h;
    }
}

// ---------------------------------------------------------------------------
// One-time: x [b][c][t] fp32  ->  stream hi/lo bf16 in [b][t][c] layout.
// ---------------------------------------------------------------------------
__global__ __launch_bounds__(256)
void transpose_split(const float* __restrict__ x,
                     unsigned short* __restrict__ shi,
                     unsigned short* __restrict__ slo) {
    __shared__ float Xt[64][65];
    const int tid = threadIdx.x;
    const int lane = tid & 63;
    const int w = tid >> 6;
    const int b = blockIdx.y;
    const int t0 = blockIdx.x * 64;
    const float* xb = x + (size_t)b * CRES * TSTR;
    #pragma unroll
    for (int i = 0; i < 16; i++) {
        const int c = w * 16 + i;
        Xt[c][lane] = xb[(size_t)c * TSTR + t0 + lane];
    }
    __syncthreads();
    const int t = tid >> 2;
    const int cq = (tid & 3) * 16;
    unsigned hw[8], lw[8];
    #pragma unroll
    for (int i = 0; i < 16; i += 2) {
        float v0 = Xt[cq + i][t];
        float v1 = Xt[cq + i + 1][t];
        unsigned short h0 = f2bf(v0), h1 = f2bf(v1);
        unsigned short l0 = f2bf(v0 - bf2f(h0)), l1 = f2bf(v1 - bf2f(h1));
        hw[i >> 1] = (unsigned)h0 | ((unsigned)h1 << 16);
        lw[i >> 1] = (unsigned)l0 | ((unsigned)l1 << 16);
    }
    size_t ob = (((size_t)b * TSTR) + t0 + t) * 64 + cq;
    *(uint4*)(shi + ob)     = make_uint4(hw[0], hw[1], hw[2], hw[3]);
    *(uint4*)(shi + ob + 8) = make_uint4(hw[4], hw[5], hw[6], hw[7]);
    *(uint4*)(slo + ob)     = make_uint4(lw[0], lw[1], lw[2], lw[3]);
    *(uint4*)(slo + ob + 8) = make_uint4(lw[4], lw[5], lw[6], lw[7]);
}

// ---------------------------------------------------------------------------
// Fused layer, MFMA version. Block = 256 threads (4 waves), NT=64 timesteps.
// Wave w owns conv/res out-channel tile [16w,16w+16) and skip tiles w, w+4.
// LDS X layout per (tap,prec): row-major [t(64)][c(64)] with 8-elem chunks
// XOR-swizzled by (t&7) -- swizzle applied on the GLOBAL source address so
// global_load_lds stays linear (1KB contiguous span per instruction,
// fully coalesced), and on the ds_read side (bank-uniform).
// Phases: stage -> conv+gate -> res(+residual) -> skip; weight fragments
// per-phase so register lifetimes don't overlap.
// 3-product bf16 hi/lo split per GEMM (fp32-equivalent precision).
// ---------------------------------------------------------------------------
__global__ __launch_bounds__(256, 3)
void layer_mfma(const unsigned short* __restrict__ in_hi,
                const unsigned short* __restrict__ in_lo,
                unsigned short* __restrict__ out_hi,
                unsigned short* __restrict__ out_lo,
                const unsigned short* __restrict__ wcat,
                const unsigned short* __restrict__ wres,
                const unsigned short* __restrict__ wskip,
                const float* __restrict__ bres,
                const float* __restrict__ bskip,
                float* __restrict__ skipout,
                int d, int Lp, int skip_start, int ntiles) {
    __shared__ __align__(16) unsigned short Xs[2][2][NT][64];  // 32 KB
    __shared__ __align__(16) unsigned short Gs[2][NT][64];     // 16 KB

    const int tid = threadIdx.x;
    const int lane = tid & 63;
    const int w = tid >> 6;
    const int b = blockIdx.y;

    // bijective XCD-aware tile swizzle (contiguous t-chunks per XCD)
    const int orig = blockIdx.x;
    const int qq = ntiles >> 3, r8 = ntiles & 7;
    const int xcd = orig & 7, sidx = orig >> 3;
    const int tile = (xcd < r8) ? (xcd * (qq + 1) + sidx)
                                : (r8 * (qq + 1) + (xcd - r8) * qq + sidx);
    const int t0 = tile * NT;

    // ---- stage both taps (hi,lo) into LDS; wave w stages segment w ----
    // instruction s covers t-rows [s*8, s*8+8): 1KB contiguous global span
    {
        const int tap = w >> 1, prec = w & 1;
        const unsigned short* src =
            (prec ? in_lo : in_hi) + (((size_t)b * TSTR) << 6);
        const int tr0 = lane >> 3;            // row within 8-row group
        const int jj = lane & 7;              // chunk within row
        const int chs = (jj ^ tr0) << 3;      // pre-swizzled source chunk
        const int toff = tap ? d : 0;
        unsigned short* lp = &Xs[tap][prec][0][0];
        #pragma unroll
        for (int s = 0; s < 8; s++) {
            const int tr = s * 8 + tr0;                       // LDS row
            const int tg = min(t0 + tr, Lp - 1) + toff;       // global row
            load_lds16(src + ((size_t)tg << 6) + chs, lp + s * 512);
        }
    }

    // ---- conv A-frags: load BEFORE the barrier (overlap with staging) ----
    short8 cAh[4], cAl[4];
    #pragma unroll
    for (int ks = 0; ks < 4; ks++) {
        const unsigned short* base = wcat + ((ks * 4 + w) * 2) * 512 + lane * 8;
        cAh[ks] = *(const short8*)base;
        cAl[ks] = *(const short8*)(base + 512);
    }

    asm volatile("s_waitcnt vmcnt(0)" ::: "memory");
    __syncthreads();

    const int cg = lane >> 4;   // k-chunk group of this lane
    const int lt = lane & 15;   // column (t) within n-tile
    const int c0 = w * 16 + cg * 4;
    const int xch = 2 * w + (cg >> 1);     // chunk holding channels c0..c0+3
    const int xcb = (cg & 1) << 2;         // offset within chunk

    // ---- conv + gate -> Gs ----
    #pragma unroll
    for (int nt = 0; nt < 4; nt++) {
        const int tl = nt * 16 + lt;
        const int sw = tl & 7;
        f32x4 acc = {0.f, 0.f, 0.f, 0.f};
        __builtin_amdgcn_s_setprio(1);
        #pragma unroll
        for (int ks = 0; ks < 4; ks++) {
            const int tap = ks >> 1;
            const int ch = (((ks & 1) * 4 + cg) ^ sw) << 3;
            short8 bh = *(const short8*)&Xs[tap][0][tl][ch];
            short8 bl = *(const short8*)&Xs[tap][1][tl][ch];
            acc = MFMA16(cAh[ks], bh, acc);
            acc = MFMA16(cAh[ks], bl, acc);
            acc = MFMA16(cAl[ks], bh, acc);
        }
        __builtin_amdgcn_s_setprio(0);
        unsigned short gh[4], gl[4];
        #pragma unroll
        for (int rr = 0; rr < 4; rr++) {
            float y = acc[rr];
            float e = __expf(-y);
            float g = (1.f - e) / fmaf(e, e, 1.f);   // tanh(y)*sigmoid(y)
            gh[rr] = f2bf(g);
            gl[rr] = f2bf(g - bf2f(gh[rr]));
        }
        const int gof = ((xch ^ sw) << 3) + xcb;
        uint2 hv, lv;
        hv.x = (unsigned)gh[0] | ((unsigned)gh[1] << 16);
        hv.y = (unsigned)gh[2] | ((unsigned)gh[3] << 16);
        lv.x = (unsigned)gl[0] | ((unsigned)gl[1] << 16);
        lv.y = (unsigned)gl[2] | ((unsigned)gl[3] << 16);
        *(uint2*)&Gs[0][tl][gof] = hv;
        *(uint2*)&Gs[1][tl][gof] = lv;
    }

    // ---- res/skip A-frags: load BEFORE barrier2 (no Gs dependence) ----
    const bool doSkip = (t0 + NT > skip_start);
    short8 rAh[2], rAl[2];
    #pragma unroll
    for (int ks = 0; ks < 2; ks++) {
        const unsigned short* base = wres + ((ks * 4 + w) * 2) * 512 + lane * 8;
        rAh[ks] = *(const short8*)base;
        rAl[ks] = *(const short8*)(base + 512);
    }
    const f32x4 brv = *(const f32x4*)(bres + c0);

    short8 sAh[2][2], sAl[2][2];
    f32x4 bsv[2];
    if (doSkip) {
        #pragma unroll
        for (int sm = 0; sm < 2; sm++) {
            const int m = w + sm * 4;
            #pragma unroll
            for (int ks = 0; ks < 2; ks++) {
                const unsigned short* base = wskip + ((ks * 8 + m) * 2) * 512 + lane * 8;
                sAh[sm][ks] = *(const short8*)base;
                sAl[sm][ks] = *(const short8*)(base + 512);
            }
            bsv[sm] = *(const f32x4*)(bskip + m * 16 + cg * 4);
        }
    }

    __syncthreads();

    unsigned short* ohb = out_hi + (((size_t)b * TSTR) << 6);
    unsigned short* olb = out_lo + (((size_t)b * TSTR) << 6);

    // ---- res phase: 1x1 + bias + residual add, write stream hi/lo ----
    #pragma unroll
    for (int nt = 0; nt < 4; nt++) {
        const int tl = nt * 16 + lt;
        const int sw = tl & 7;
        short8 gbh[2], gbl[2];
        #pragma unroll
        for (int ks = 0; ks < 2; ks++) {
            const int ch = ((ks * 4 + cg) ^ sw) << 3;
            gbh[ks] = *(const short8*)&Gs[0][tl][ch];
            gbl[ks] = *(const short8*)&Gs[1][tl][ch];
        }
        f32x4 racc = {0.f, 0.f, 0.f, 0.f};
        __builtin_amdgcn_s_setprio(1);
        #pragma unroll
        for (int ks = 0; ks < 2; ks++) {
            racc = MFMA16(rAh[ks], gbh[ks], racc);
            racc = MFMA16(rAh[ks], gbl[ks], racc);
            racc = MFMA16(rAl[ks], gbh[ks], racc);
        }
        __builtin_amdgcn_s_setprio(0);
        const int tp = t0 + tl;
        if (tp < Lp) {
            const int xof = ((xch ^ sw) << 3) + xcb;
            uint2 xh = *(const uint2*)&Xs[1][0][tl][xof];
            uint2 xl = *(const uint2*)&Xs[1][1][tl][xof];
            float v0 = racc[0] + brv[0] + bf2f(xh.x) + bf2f(xl.x);
            float v1 = racc[1] + brv[1] + bf2f(xh.x >> 16) + bf2f(xl.x >> 16);
            float v2 = racc[2] + brv[2] + bf2f(xh.y) + bf2f(xl.y);
            float v3 = racc[3] + brv[3] + bf2f(xh.y >> 16) + bf2f(xl.y >> 16);
            unsigned short oh0 = f2bf(v0), oh1 = f2bf(v1), oh2 = f2bf(v2), oh3 = f2bf(v3);
            uint2 hv, lv;
            hv.x = (unsigned)oh0 | ((unsigned)oh1 << 16);
            hv.y = (unsigned)oh2 | ((unsigned)oh3 << 16);
            lv.x = (unsigned)f2bf(v0 - bf2f(oh0)) | ((unsigned)f2bf(v1 - bf2f(oh1)) << 16);
            lv.y = (unsigned)f2bf(v2 - bf2f(oh2)) | ((unsigned)f2bf(v3 - bf2f(oh3)) << 16);
            const size_t ob = ((size_t)tp << 6) + c0;
            *(uint2*)(ohb + ob) = hv;
            *(uint2*)(olb + ob) = lv;
        }
    }

    // ---- skip phase (block-uniform predicate: MFMA with full exec mask) ----
    if (doSkip) {
        float* skb = skipout + (size_t)b * CSKIP * SKIPN;
        #pragma unroll
        for (int nt = 0; nt < 4; nt++) {
            const int tl = nt * 16 + lt;
            const int sw = tl & 7;
            short8 gbh[2], gbl[2];
            #pragma unroll
            for (int ks = 0; ks < 2; ks++) {
                const int ch = ((ks * 4 + cg) ^ sw) << 3;
                gbh[ks] = *(const short8*)&Gs[0][tl][ch];
                gbl[ks] = *(const short8*)&Gs[1][tl][ch];
            }
            const int tp = t0 + tl;
            #pragma unroll
            for (int sm = 0; sm < 2; sm++) {
                f32x4 sacc = {0.f, 0.f, 0.f, 0.f};
                __builtin_amdgcn_s_setprio(1);
                #pragma unroll
                for (int ks = 0; ks < 2; ks++) {
                    sacc = MFMA16(sAh[sm][ks], gbh[ks], sacc);
                    sacc = MFMA16(sAh[sm][ks], gbl[ks], sacc);
                    sacc = MFMA16(sAl[sm][ks], gbh[ks], sacc);
                }
                __builtin_amdgcn_s_setprio(0);
                if (tp >= skip_start && tp < Lp) {
                    const int c2 = (w + sm * 4) * 16 + cg * 4;
                    float* sp = skb + (size_t)c2 * SKIPN + (tp - skip_start);
                    sp[0]         = sacc[0] + bsv[sm][0];
                    sp[SKIPN]     = sacc[1] + bsv[sm][1];
                    sp[2 * SKIPN] = sacc[2] + bsv[sm][2];
                    sp[3 * SKIPN] = sacc[3] + bsv[sm][3];
                }
            }
        }
    }
}

// ---------------------------------------------------------------------------
// Host: repack + transpose once, then 40 stream-ordered layer launches.
// ws: s0h|s0l|s1h|s1l (4 x 8 MiB) | wcatP | wresP | wskipP  (~35.3 MB)
// ---------------------------------------------------------------------------
extern "C" void kernel_launch(void* const* d_in, const int* in_sizes, int n_in,
                              void* d_out, int out_size, void* d_ws, size_t ws_size,
                              hipStream_t stream) {
    const float* x = (const float*)d_in[0];
    const float* wdil = (const float*)d_in[1];
    const float* wres = (const float*)d_in[2];
    const float* bres = (const float*)d_in[3];
    const float* wskip = (const float*)d_in[4];
    const float* bskip = (const float*)d_in[5];
    float* out = (float*)d_out;

    const size_t SELEMS = (size_t)NB * TSTR * 64;
    unsigned short* s0h = (unsigned short*)d_ws;
    unsigned short* s0l = s0h + SELEMS;
    unsigned short* s1h = s0l + SELEMS;
    unsigned short* s1l = s1h + SELEMS;
    unsigned short* wcatP = s1l + SELEMS;
    unsigned short* wresP = wcatP + (size_t)N_LAYERS * WCAT_L;
    unsigned short* wskipP = wresP + (size_t)N_LAYERS * WRES_L;

    {
        const int total = N_LAYERS * (WCAT_L + WRES_L + WSKIP_L);
        repack_mfma<<<(total + 255) / 256, 256, 0, stream>>>(
            wdil, wres, wskip, wcatP, wresP, wskipP);
    }
    transpose_split<<<dim3(TSTR / 64, NB), 256, 0, stream>>>(x, s0h, s0l);

    int L = TSTR;
    unsigned short *cih = s0h, *cil = s0l, *coh = s1h, *col = s1l;
    for (int i = 0; i < N_LAYERS; i++) {
        const int d = 1 << (i % 10);
        const int Lp = L - d;
        const int ntiles = (Lp + NT - 1) / NT;
        layer_mfma<<<dim3(ntiles, NB), 256, 0, stream>>>(
            cih, cil, coh, col,
            wcatP + (size_t)i * WCAT_L,
            wresP + (size_t)i * WRES_L,
            wskipP + (size_t)i * WSKIP_L,
            bres + (size_t)i * CRES,
            bskip + (size_t)i * CSKIP,
            out + (size_t)i * NB * CSKIP * SKIPN,
            d, Lp, Lp - SKIPN, ntiles);
        unsigned short* th = cih; cih = coh; coh = th;
        unsigned short* tl2 = cil; cil = col; col = tl2;
        L = Lp;
    }
}